// Round 11
// baseline (363.863 us; speedup 1.0000x reference)
//
#include <hip/hip_runtime.h>
#include <hip/hip_cooperative_groups.h>

namespace cg = cooperative_groups;

#define N_NODES 50000
#define N_EDGES 800000
#define CH 64
#define OUT_OFF_STD (N_NODES * CH)        // 3,200,000
#define OUT_OFF_KL  (2 * N_NODES * CH)    // 6,400,000
#define CAP 64                            // slots/node; in-degree ~Poisson(16)
#define NGRP 8                            // XCD groups (blockIdx & 7 heuristic)
#define NPG 6250                          // nodes per group
#define GEMM_TILES 782                    // ceil(50000/64)
#define EDGE_CHUNKS 3125                  // 3125*256 = 800000 exact
#define GQ 1563                           // node-quads per group (ceil 6250/4)

typedef __attribute__((ext_vector_type(8))) short short8;
typedef __attribute__((ext_vector_type(4))) float f32x4;

__device__ __forceinline__ int rl_i(unsigned v, int lane) {
    return __builtin_amdgcn_readlane((int)v, lane);
}
// fp32 -> bf16 round-to-nearest-even (returns low 16 bits)
__device__ __forceinline__ unsigned f2bf(float f) {
    unsigned u = __float_as_uint(f);
    return (u + 0x7fffu + ((u >> 16) & 1u)) >> 16;
}
// pack (src, w) -> 1 dword: src<<15 | round(w*32768) clamped to 15 bits
__device__ __forceinline__ unsigned pack_edge(int src, float w) {
    unsigned wq = (unsigned)(w * 32768.0f + 0.5f);
    if (wq > 32767u) wq = 32767u;
    return ((unsigned)src << 15) | wq;
}

// ---------------- shared device routines (used by mono + fallback) ----------

__device__ __forceinline__ void gemm_tile(
    int row0, int lane,
    const float* __restrict__ mean, const float* __restrict__ stdv,
    const unsigned short* __restrict__ fragBm,
    const unsigned short* __restrict__ fragBv,
    unsigned* __restrict__ sup)
{
    const int m = lane & 15;             // A row within tile
    const int q = (lane >> 4) & 3;       // k quad
    const float* mrow = mean + (size_t)(row0 + m) * CH + q * 8;
    const float* srow = stdv + (size_t)(row0 + m) * CH + q * 8;

    short8 aM[2], aV[2];
#pragma unroll
    for (int h = 0; h < 2; ++h) {        // k = h*32 + q*8 + j
        float4 x0 = *(const float4*)(mrow + h * 32);
        float4 x1 = *(const float4*)(mrow + h * 32 + 4);
        float4 s0 = *(const float4*)(srow + h * 32);
        float4 s1 = *(const float4*)(srow + h * 32 + 4);
        aM[h][0] = (short)f2bf(x0.x); aM[h][1] = (short)f2bf(x0.y);
        aM[h][2] = (short)f2bf(x0.z); aM[h][3] = (short)f2bf(x0.w);
        aM[h][4] = (short)f2bf(x1.x); aM[h][5] = (short)f2bf(x1.y);
        aM[h][6] = (short)f2bf(x1.z); aM[h][7] = (short)f2bf(x1.w);
        aV[h][0] = (short)f2bf(s0.x * s0.x); aV[h][1] = (short)f2bf(s0.y * s0.y);
        aV[h][2] = (short)f2bf(s0.z * s0.z); aV[h][3] = (short)f2bf(s0.w * s0.w);
        aV[h][4] = (short)f2bf(s1.x * s1.x); aV[h][5] = (short)f2bf(s1.y * s1.y);
        aV[h][6] = (short)f2bf(s1.z * s1.z); aV[h][7] = (short)f2bf(s1.w * s1.w);
    }

    f32x4 accM[4], accV[4];
#pragma unroll
    for (int c = 0; c < 4; ++c) { accM[c] = (f32x4)0.0f; accV[c] = (f32x4)0.0f; }
#pragma unroll
    for (int c = 0; c < 4; ++c) {
#pragma unroll
        for (int h = 0; h < 2; ++h) {
            short8 bm = *(const short8*)(fragBm + ((c * 2 + h) * 64 + lane) * 8);
            short8 bv = *(const short8*)(fragBv + ((c * 2 + h) * 64 + lane) * 8);
            accM[c] = __builtin_amdgcn_mfma_f32_16x16x32_bf16(aM[h], bm, accM[c], 0, 0, 0);
            accV[c] = __builtin_amdgcn_mfma_f32_16x16x32_bf16(aV[h], bv, accV[c], 0, 0, 0);
        }
    }
    // C/D layout: col = lane&15, row = (lane>>4)*4 + reg  [m89-verified]
    const int rg = lane >> 4;
#pragma unroll
    for (int c = 0; c < 4; ++c)
#pragma unroll
        for (int r = 0; r < 4; ++r) {
            int node = row0 + rg * 4 + r;
            sup[(size_t)node * CH + c * 16 + m] =
                f2bf(accM[c][r]) | (f2bf(accV[c][r]) << 16);
        }
}

__device__ __forceinline__ void gather_quad(
    int n, int lane,
    const int* __restrict__ cur, const unsigned* __restrict__ bins,
    const unsigned* __restrict__ sup, float* __restrict__ out)
{
    int cnt = cur[n];
    if (cnt > CAP) cnt = CAP;
    unsigned p = 0u;
    if (lane < cnt) p = bins[(size_t)n * CAP + lane];

    float accM = 0.0f, accV = 0.0f;
    for (int i = 0; i < cnt; i += 8) {
        unsigned u[8];
#pragma unroll
        for (int t = 0; t < 8; ++t)
            u[t] = (i + t < cnt) ? (unsigned)rl_i(p, i + t) : 0u;   // w=0 when idle
        unsigned q[8];
#pragma unroll
        for (int t = 0; t < 8; ++t)
            q[t] = sup[(size_t)(u[t] >> 15) * CH + lane];
#pragma unroll
        for (int t = 0; t < 8; ++t) {
            float w = (float)(u[t] & 0x7FFFu) * (1.0f / 32768.0f);
            float mm = __uint_as_float(q[t] << 16);
            float vv = __uint_as_float(q[t] & 0xFFFF0000u);
            accM += w * mm;
            accV += (w * w) * vv;
        }
    }
    out[(size_t)n * CH + lane] = accM;
    out[OUT_OFF_STD + (size_t)n * CH + lane] = sqrtf(expf(accV) + 1e-6f);
}

// ---------------------------------------------------------------------------
// Cooperative mono kernel (grid-size agnostic; grid multiple of 8).
//  A: grid-stride zero cur | block 0: W->bf16 B-frags (swizzled) + KL
//  B: blocks [0, grid/4): grid-stride MFMA gemm tiles
//     blocks [grid/4, grid): XCD-affine fill (g = fb&7) -> packed bins
//  C: XCD-affine pull-gather + fused epilogue
// ---------------------------------------------------------------------------
__global__ __launch_bounds__(256) void mono_kernel(
    const float* __restrict__ mean, const float* __restrict__ stdv,
    const int* __restrict__ ei, const float* __restrict__ ew,
    const float* __restrict__ mu_m, const float* __restrict__ ls_m,
    const float* __restrict__ eps_m,
    const float* __restrict__ mu_s, const float* __restrict__ ls_s,
    const float* __restrict__ eps_s,
    int* __restrict__ cur, unsigned* __restrict__ bins,
    unsigned* __restrict__ sup,
    unsigned short* __restrict__ fragBm, unsigned short* __restrict__ fragBv,
    float* __restrict__ out)
{
    cg::grid_group grid = cg::this_grid();
    const int bid = blockIdx.x;
    const int tid = threadIdx.x;
    const int lane = tid & 63, wave = tid >> 6;
    const int nthreads = gridDim.x * 256;

    __shared__ unsigned short Wm[CH * CH];
    __shared__ unsigned short Wv[CH * CH];
    __shared__ float red[4];

    // ================= Phase A =================
    for (int i = bid * 256 + tid; i < N_NODES; i += nthreads)
        cur[i] = 0;
    if (bid == 0) {
        float kl = 0.0f;
        for (int i = tid; i < CH * CH; i += 256) {
            float mu = mu_m[i], ls = ls_m[i];
            Wm[i] = (unsigned short)f2bf(mu + eps_m[i] * expf(ls));
            kl += 0.5f * (expf(2.0f * ls) + mu * mu - 2.0f * ls - 1.0f);
            mu = mu_s[i]; ls = ls_s[i];
            Wv[i] = (unsigned short)f2bf(mu + eps_s[i] * expf(ls));
            kl += 0.5f * (expf(2.0f * ls) + mu * mu - 2.0f * ls - 1.0f);
        }
        __syncthreads();
        // fragB[((c*2+h)*64+l)*8+j] = W[h*32+(l>>4)*8+j][c*16+(l&15)]
        for (int f = tid; f < CH * CH; f += 256) {
            int j = f & 7, l = (f >> 3) & 63, ch = f >> 9;
            int k = (ch & 1) * 32 + ((l >> 4) & 3) * 8 + j;
            int n = (ch >> 1) * 16 + (l & 15);
            fragBm[f] = Wm[k * CH + n];
            fragBv[f] = Wv[k * CH + n];
        }
        for (int off = 32; off > 0; off >>= 1)
            kl += __shfl_down(kl, off, 64);
        if ((tid & 63) == 0) red[tid >> 6] = kl;
        __syncthreads();
        if (tid == 0)
            out[OUT_OFF_KL] = red[0] + red[1] + red[2] + red[3];
    }

    grid.sync();

    // ================= Phase B =================
    const int G = gridDim.x >> 2;                  // gemm blocks
    if (bid < G) {
        for (int t = bid; t < GEMM_TILES; t += G) {
            int row0 = t * 64 + wave * 16;
            if (row0 < N_NODES)
                gemm_tile(row0, lane, mean, stdv, fragBm, fragBv, sup);
        }
    } else {
        const int fb = bid - G;
        const int F = gridDim.x - G;
        const int g = fb & (NGRP - 1);
        const int ci = fb >> 3;
        const int ng = (F >> 3) + (((F & 7) > g) ? 1 : 0);
        const int lo = g * NPG;
        for (int c = ci; c < EDGE_CHUNKS; c += ng) {
            int e = c * 256 + tid;
            int dst = ei[N_EDGES + e];
            if ((unsigned)(dst - lo) < (unsigned)NPG) {
                int src = ei[e];
                float w = ew[e];
                int slot = atomicAdd(&cur[dst], 1);
                if (slot < CAP)
                    bins[(size_t)dst * CAP + slot] = pack_edge(src, w);
            }
        }
    }

    grid.sync();

    // ================= Phase C: XCD-affine gather =================
    const int g = bid & (NGRP - 1);
    const int wg = bid >> 3;
    const int stride = gridDim.x >> 3;
    for (int qi = wg; qi < GQ; qi += stride) {
        const int loc = qi * 4 + wave;
        if (loc < NPG)
            gather_quad(g * NPG + loc, lane, cur, bins, sup, out);
    }
}

// ---------------------------- fallback path (R9) ---------------------------

__global__ __launch_bounds__(256) void wkl_kernel(
    const float* __restrict__ mu_m, const float* __restrict__ ls_m,
    const float* __restrict__ eps_m,
    const float* __restrict__ mu_s, const float* __restrict__ ls_s,
    const float* __restrict__ eps_s,
    unsigned short* __restrict__ fragBm, unsigned short* __restrict__ fragBv,
    float* __restrict__ kl_out)
{
    __shared__ unsigned short Wm[CH * CH];
    __shared__ unsigned short Wv[CH * CH];
    float kl = 0.0f;
    for (int i = threadIdx.x; i < CH * CH; i += 256) {
        float mu = mu_m[i], ls = ls_m[i];
        Wm[i] = (unsigned short)f2bf(mu + eps_m[i] * expf(ls));
        kl += 0.5f * (expf(2.0f * ls) + mu * mu - 2.0f * ls - 1.0f);
        mu = mu_s[i]; ls = ls_s[i];
        Wv[i] = (unsigned short)f2bf(mu + eps_s[i] * expf(ls));
        kl += 0.5f * (expf(2.0f * ls) + mu * mu - 2.0f * ls - 1.0f);
    }
    __syncthreads();
    for (int f = threadIdx.x; f < CH * CH; f += 256) {
        int j = f & 7, l = (f >> 3) & 63, ch = f >> 9;
        int k = (ch & 1) * 32 + ((l >> 4) & 3) * 8 + j;
        int n = (ch >> 1) * 16 + (l & 15);
        fragBm[f] = Wm[k * CH + n];
        fragBv[f] = Wv[k * CH + n];
    }
    for (int off = 32; off > 0; off >>= 1)
        kl += __shfl_down(kl, off, 64);
    __shared__ float red[4];
    if ((threadIdx.x & 63) == 0) red[threadIdx.x >> 6] = kl;
    __syncthreads();
    if (threadIdx.x == 0)
        kl_out[0] = red[0] + red[1] + red[2] + red[3];
}

#define FB_FILL_BLOCKS 3128   // 391 chunks x 8 groups
__global__ __launch_bounds__(256) void gemfill_kernel(
    const float* __restrict__ mean, const float* __restrict__ stdv,
    const unsigned short* __restrict__ fragBm,
    const unsigned short* __restrict__ fragBv,
    const int* __restrict__ ei, const float* __restrict__ ew,
    int* __restrict__ cur, unsigned* __restrict__ bins,
    unsigned* __restrict__ sup)
{
    const int tid = threadIdx.x;
    if (blockIdx.x < FB_FILL_BLOCKS) {
        const int g = blockIdx.x & (NGRP - 1);
        const int chunk = blockIdx.x >> 3;
        const int base = chunk * 2048;
        const int lo = g * NPG;
#pragma unroll
        for (int r = 0; r < 8; ++r) {
            int e = base + r * 256 + tid;
            if (e < N_EDGES) {
                int dst = ei[N_EDGES + e];
                if ((unsigned)(dst - lo) < (unsigned)NPG) {
                    int slot = atomicAdd(&cur[dst], 1);
                    if (slot < CAP)
                        bins[(size_t)dst * CAP + slot] = pack_edge(ei[e], ew[e]);
                }
            }
        }
        return;
    }
    const int lane = tid & 63, wave = tid >> 6;
    const int row0 = (blockIdx.x - FB_FILL_BLOCKS) * 64 + wave * 16;
    if (row0 >= N_NODES) return;
    gemm_tile(row0, lane, mean, stdv, fragBm, fragBv, sup);
}

__global__ __launch_bounds__(256) void gather_kernel(
    const int* __restrict__ cur, const unsigned* __restrict__ bins,
    const unsigned* __restrict__ sup, float* __restrict__ out)
{
    const int g = blockIdx.x & (NGRP - 1);
    const int cid = blockIdx.x >> 3;
    const int wave = threadIdx.x >> 6;
    const int lane = threadIdx.x & 63;
    const int loc = cid * 4 + wave;
    if (loc >= NPG) return;
    gather_quad(g * NPG + loc, lane, cur, bins, sup, out);
}

extern "C" void kernel_launch(void* const* d_in, const int* in_sizes, int n_in,
                              void* d_out, int out_size, void* d_ws, size_t ws_size,
                              hipStream_t stream)
{
    const float* mean  = (const float*)d_in[0];
    const float* stdv  = (const float*)d_in[1];
    const int*   ei    = (const int*)d_in[2];
    const float* ew    = (const float*)d_in[3];
    const float* mu_m  = (const float*)d_in[4];
    const float* ls_m  = (const float*)d_in[5];
    const float* eps_m = (const float*)d_in[6];
    const float* mu_s  = (const float*)d_in[7];
    const float* ls_s  = (const float*)d_in[8];
    const float* eps_s = (const float*)d_in[9];

    float* out = (float*)d_out;
    // ws layout (16B-aligned): cur | sup | bins(u32) | fragBm | fragBv
    int*            cur    = (int*)d_ws;                            // 50000 i
    unsigned*       sup    = (unsigned*)(cur + N_NODES);            // 3.2M u32
    unsigned*       bins   = (unsigned*)(sup + (size_t)N_NODES * CH); // 3.2M u32
    unsigned short* fragBm = (unsigned short*)(bins + (size_t)N_NODES * CAP);
    unsigned short* fragBv = fragBm + CH * CH;

    // size cooperative grid from the occupancy API (host code runs only at
    // capture time); fall back to the proven 3-dispatch path on any failure.
    int blocksPerCU = 0;
    hipError_t qerr = hipOccupancyMaxActiveBlocksPerMultiprocessor(
        &blocksPerCU, mono_kernel, 256, 0);
    int grid = 0;
    if (qerr == hipSuccess && blocksPerCU > 0) {
        grid = blocksPerCU * 256;          // 256 CUs on MI355X
        if (grid > 2048) grid = 2048;
        grid &= ~7;                        // multiple of 8 for group math
    }

    hipError_t lerr = hipErrorUnknown;
    if (grid >= 64) {
        void* args[] = {
            (void*)&mean, (void*)&stdv, (void*)&ei, (void*)&ew,
            (void*)&mu_m, (void*)&ls_m, (void*)&eps_m,
            (void*)&mu_s, (void*)&ls_s, (void*)&eps_s,
            (void*)&cur, (void*)&bins, (void*)&sup,
            (void*)&fragBm, (void*)&fragBv, (void*)&out
        };
        lerr = hipLaunchCooperativeKernel((const void*)mono_kernel,
                                          dim3(grid), dim3(256), args, 0, stream);
    }
    if (lerr != hipSuccess) {
        hipMemsetAsync(cur, 0, N_NODES * sizeof(int), stream);
        wkl_kernel<<<1, 256, 0, stream>>>(mu_m, ls_m, eps_m, mu_s, ls_s, eps_s,
                                          fragBm, fragBv, out + OUT_OFF_KL);
        gemfill_kernel<<<FB_FILL_BLOCKS + GEMM_TILES, 256, 0, stream>>>(
            mean, stdv, fragBm, fragBv, ei, ew, cur, bins, sup);
        gather_kernel<<<NGRP * GQ, 256, 0, stream>>>(cur, bins, sup, out);
    }
}